// Round 1
// baseline (502.839 us; speedup 1.0000x reference)
//
#include <hip/hip_runtime.h>

// x: [B=16, C=64, H=256, W=256] fp32
// out = sigmoid(conv3x3(concat([max_c x, mean_c x]), w, SAME)) * x
//
// Layout v2 (vectorized + XCD-swizzled):
//  - thread = 4 consecutive pixels x 16 channels -> 16x global_load_dwordx4
//    (64 payload VGPRs, pinned across the barrier), pooled partials combined
//    across the 4 channel-group lanes via shfl_xor(8|16) (in-wave by
//    construction: lane = qx(3b) | g(2b) | qy&1).
//  - XCD-chunked wgid swizzle: 4096 blocks = 8 XCDs x 512; each XCD owns 2
//    full batches, walking wtile fastest -> every spatial neighbor tile is
//    on the SAME XCD at +-1/+-8 dispatch distance, so the halo ring re-reads
//    (esp. the scattered side columns) hit that XCD's L2 instead of HBM.
//  - halo: 2 threads x 32 channels per ring pixel (pair-combined via
//    shfl_xor(1)) -> halves the serial halo load chain.
//  - out stored nontemporal: write-once data must not evict x tiles from L2.

typedef float f32x4 __attribute__((ext_vector_type(4)));

#define TW 32
#define TH 8

__global__ __launch_bounds__(256) void spatial_attn_fused(
    const float* __restrict__ x,
    const float* __restrict__ wgt,
    float* __restrict__ out)
{
    constexpr int C = 64, H = 256, W = 256;
    constexpr int CG = 16;   // channels per thread

    // ---- XCD-chunked swizzle (presumes round-robin wgid%8 -> XCD) ----
    // grid = (8 wtiles, 32 htiles, 16 b) = 4096 blocks, 512 per XCD,
    // 256 tiles per batch -> each XCD gets exactly 2 whole batches.
    const int lin = blockIdx.x + (int)gridDim.x * (blockIdx.y + (int)gridDim.y * blockIdx.z);
    const int xcd = lin & 7;
    const int nid = xcd * 512 + (lin >> 3);   // bijective: 4096 % 8 == 0
    const int b   = nid >> 8;                 // 256 tiles / batch
    const int rem = nid & 255;
    const int th  = (rem >> 3) * TH;          // htile 0..31
    const int tw  = (rem & 7) * TW;           // wtile 0..7 (fastest -> horiz neighbors adjacent in time)

    const int tid = threadIdx.x;
    const int qx  = tid & 7;          // pixel-quad column 0..7 (pixels qx*4..qx*4+3)
    const int g   = (tid >> 3) & 3;   // channel group 0..3 (16 ch each)
    const int qy  = tid >> 5;         // row in tile 0..7

    const int h = th + qy;
    const int w = tw + qx * 4;

    __shared__ float smax[TH + 2][TW + 3];   // stride 35: conv rows land on disjoint banks
    __shared__ float savg[TH + 2][TW + 3];

    const size_t cstride = (size_t)H * W;                              // 65536
    const size_t base    = ((size_t)(b * C + g * CG) * H + h) * W + w;

    // ---- interior: 16 channels x 4 pixels -> registers, pool in-register ----
    f32x4 xv[CG];
    f32x4 mx4 = { -INFINITY, -INFINITY, -INFINITY, -INFINITY };
    f32x4 sm4 = { 0.0f, 0.0f, 0.0f, 0.0f };
#pragma unroll
    for (int i = 0; i < CG; ++i) {
        f32x4 v = *reinterpret_cast<const f32x4*>(x + base + (size_t)i * cstride);
        xv[i] = v;
        mx4.x = fmaxf(mx4.x, v.x);  mx4.y = fmaxf(mx4.y, v.y);
        mx4.z = fmaxf(mx4.z, v.z);  mx4.w = fmaxf(mx4.w, v.w);
        sm4 += v;
    }
    // Pin the payload in VGPRs: forbids rematerializing the x loads after
    // the barrier (round-1 compiler sank them -> x read twice from HBM).
#pragma unroll
    for (int i = 0; i < CG; ++i) asm volatile("" : "+v"(xv[i]));

    // combine the 4 channel groups (lane bits 3..4) -> full 64-ch pool per pixel
#pragma unroll
    for (int mask = 8; mask <= 16; mask <<= 1) {
        mx4.x = fmaxf(mx4.x, __shfl_xor(mx4.x, mask));
        mx4.y = fmaxf(mx4.y, __shfl_xor(mx4.y, mask));
        mx4.z = fmaxf(mx4.z, __shfl_xor(mx4.z, mask));
        mx4.w = fmaxf(mx4.w, __shfl_xor(mx4.w, mask));
        sm4.x += __shfl_xor(sm4.x, mask);
        sm4.y += __shfl_xor(sm4.y, mask);
        sm4.z += __shfl_xor(sm4.z, mask);
        sm4.w += __shfl_xor(sm4.w, mask);
    }

    if (g == 0) {
#pragma unroll
        for (int j = 0; j < 4; ++j) {
            smax[qy + 1][qx * 4 + 1 + j] = mx4[j];
            savg[qy + 1][qx * 4 + 1 + j] = sm4[j] * (1.0f / 64.0f);
        }
    }

    // ---- halo ring: 84 pixels, 2 threads x 32 channels each ----
    if (tid < 168) {
        const int hp   = tid >> 1;   // halo pixel 0..83
        const int half = tid & 1;    // channel half
        int hy, hx;
        if (hp < 34)      { hy = 0;              hx = hp;        }
        else if (hp < 68) { hy = TH + 1;         hx = hp - 34;   }
        else if (hp < 76) { hy = 1 + (hp - 68);  hx = 0;         }
        else              { hy = 1 + (hp - 76);  hx = TW + 1;    }
        const int gh = th + hy - 1;
        const int gw = tw + hx - 1;
        float m2 = 0.0f, s2 = 0.0f;             // zero-padding outside the image
        if (gh >= 0 && gh < H && gw >= 0 && gw < W) {
            const size_t hidx = ((size_t)(b * C + half * 32) * H + gh) * W + gw;
            m2 = -INFINITY;
#pragma unroll 8
            for (int c = 0; c < 32; ++c) {
                float v = x[hidx + (size_t)c * cstride];
                m2 = fmaxf(m2, v);
                s2 += v;
            }
        }
        // pair lanes (2p, 2p+1) are adjacent -> both active together
        m2 = fmaxf(m2, __shfl_xor(m2, 1));
        s2 += __shfl_xor(s2, 1);
        if (half == 0) {
            smax[hy][hx] = m2;
            savg[hy][hx] = s2 * (1.0f / 64.0f);
        }
    }
    __syncthreads();

    // ---- 3x3 conv (cross-correlation) + sigmoid, per thread's 4 pixels ----
    // all 4 g-lanes compute identical attn (cheap; VALU is at 8%)
    f32x4 att;
#pragma unroll
    for (int j = 0; j < 4; ++j) {
        const int px = qx * 4 + j;
        float acc = 0.0f;
#pragma unroll
        for (int kh = 0; kh < 3; ++kh) {
#pragma unroll
            for (int kw = 0; kw < 3; ++kw) {
                acc += wgt[kh * 3 + kw]     * smax[qy + kh][px + kw];
                acc += wgt[9 + kh * 3 + kw] * savg[qy + kh][px + kw];
            }
        }
        att[j] = 1.0f / (1.0f + __expf(-acc));
    }

    // ---- broadcast multiply from the pinned registers, nontemporal store ----
#pragma unroll
    for (int i = 0; i < CG; ++i) {
        f32x4 o = xv[i] * att;
        __builtin_nontemporal_store(o, reinterpret_cast<f32x4*>(out + base + (size_t)i * cstride));
    }
}

extern "C" void kernel_launch(void* const* d_in, const int* in_sizes, int n_in,
                              void* d_out, int out_size, void* d_ws, size_t ws_size,
                              hipStream_t stream) {
    const float* x   = (const float*)d_in[0];
    const float* wgt = (const float*)d_in[1];
    float* out = (float*)d_out;

    dim3 grid(256 / TW, 256 / TH, 16);   // (wtiles=8, htiles=32, batch=16)
    dim3 block(256);
    spatial_attn_fused<<<grid, block, 0, stream>>>(x, wgt, out);
}